// Round 1
// baseline (497.727 us; speedup 1.0000x reference)
//
#include <hip/hip_runtime.h>

#define G 128
#define P 512
#define K 16
#define NPTS (G * P)   // 65536

// ---------------------------------------------------------------------------
// KNN: one block per graph, 512 threads (1 target each).
// Exact replication of lax.top_k(-d2, K) tie-breaking via integer key
// (d2 << 9) | src_idx  (d2 <= 1922 < 2^11, idx < 2^9).
// ---------------------------------------------------------------------------
__global__ __launch_bounds__(P)
void knn_kernel(const int* __restrict__ coo, int* __restrict__ idx_out) {
    __shared__ int sx[P];
    __shared__ int sy[P];
    const int g = blockIdx.x;
    const int t = threadIdx.x;        // target point (local)
    const int base = g * P;

    sx[t] = coo[(base + t) * 3 + 0];
    sy[t] = coo[(base + t) * 3 + 1];
    __syncthreads();

    const int px = sx[t];
    const int py = sy[t];

    unsigned best[K];
#pragma unroll
    for (int k = 0; k < K; ++k) best[k] = 0xFFFFFFFFu;
    unsigned worst = 0xFFFFFFFFu;
    int wi = 0;

    for (int s = 0; s < P; ++s) {
        if (s == t) continue;                 // loop=False
        const int dx = px - sx[s];
        const int dy = py - sy[s];
        const unsigned d2 = (unsigned)(dx * dx + dy * dy);
        const unsigned key = (d2 << 9) | (unsigned)s;
        if (key < worst) {
            best[wi] = key;
            // recompute current worst of the 16
            worst = best[0]; wi = 0;
#pragma unroll
            for (int k = 1; k < K; ++k) {
                if (best[k] > worst) { worst = best[k]; wi = k; }
            }
        }
    }
#pragma unroll
    for (int k = 0; k < K; ++k)
        idx_out[(base + t) * K + k] = (int)(best[k] & (unsigned)(P - 1));
}

// ---------------------------------------------------------------------------
// Neighbor mean: one block per point, channels across threads (coalesced).
// ---------------------------------------------------------------------------
template <int NIN>
__global__ __launch_bounds__(128)
void gather_mean_kernel(const float* __restrict__ h, const int* __restrict__ idx,
                        float* __restrict__ nbr) {
    const int n = blockIdx.x;          // global point id
    const int g = n >> 9;              // / P
    __shared__ int nb[K];
    if (threadIdx.x < K) nb[threadIdx.x] = idx[n * K + threadIdx.x];
    __syncthreads();

    const float* hg = h + (size_t)(g * P) * NIN;
    for (int c = threadIdx.x; c < NIN; c += 128) {
        float acc = 0.f;
#pragma unroll
        for (int k = 0; k < K; ++k) acc += hg[nb[k] * NIN + c];
        nbr[(size_t)n * NIN + c] = acc * (1.0f / 16.0f);
    }
}

// ---------------------------------------------------------------------------
// SAGE layer: out = relu(nbr @ wl + h @ wr + b)
// Block: 256 threads handles 64 points x NOUT outputs.
// Thread t -> point (t & 63), out-group (t >> 6) of NOUT/4 outputs.
// Within a wave the out-group is constant -> weight LDS reads are
// same-address broadcasts; h/nbr LDS rows padded to 33 -> conflict-free.
// ---------------------------------------------------------------------------
template <int NIN, int NOUT>
__global__ __launch_bounds__(256)
void sage_kernel(const float* __restrict__ nbr, const float* __restrict__ h,
                 const float* __restrict__ wl, const float* __restrict__ wr,
                 const float* __restrict__ bias, float* __restrict__ out) {
    constexpr int TI = 32;              // i-tile
    constexpr int JPT = NOUT / 4;       // outputs per thread

    __shared__ float hs[64][TI + 1];
    __shared__ float ns[64][TI + 1];
    __shared__ float wls[TI * NOUT];
    __shared__ float wrs[TI * NOUT];

    const int tid = threadIdx.x;
    const int pt  = tid & 63;
    const int og  = tid >> 6;
    const int o0  = og * JPT;
    const int n0  = blockIdx.x * 64;

    float acc[JPT];
#pragma unroll
    for (int j = 0; j < JPT; ++j) acc[j] = 0.f;

    for (int it = 0; it < NIN; it += TI) {
        __syncthreads();   // protect previous tile's LDS reads
        // stage h / nbr tiles: row = tid>>2, 8 consecutive cols per thread
        {
            const int r  = tid >> 2;
            const int c0 = (tid & 3) * 8;
            const float* hp = h   + (size_t)(n0 + r) * NIN + it + c0;
            const float* np = nbr + (size_t)(n0 + r) * NIN + it + c0;
            float4 a0 = *(const float4*)hp;
            float4 a1 = *(const float4*)(hp + 4);
            float4 b0v = *(const float4*)np;
            float4 b1v = *(const float4*)(np + 4);
            hs[r][c0 + 0] = a0.x; hs[r][c0 + 1] = a0.y;
            hs[r][c0 + 2] = a0.z; hs[r][c0 + 3] = a0.w;
            hs[r][c0 + 4] = a1.x; hs[r][c0 + 5] = a1.y;
            hs[r][c0 + 6] = a1.z; hs[r][c0 + 7] = a1.w;
            ns[r][c0 + 0] = b0v.x; ns[r][c0 + 1] = b0v.y;
            ns[r][c0 + 2] = b0v.z; ns[r][c0 + 3] = b0v.w;
            ns[r][c0 + 4] = b1v.x; ns[r][c0 + 5] = b1v.y;
            ns[r][c0 + 6] = b1v.z; ns[r][c0 + 7] = b1v.w;
        }
        // stage weight tiles (whole contiguous i-rows)
        for (int e = tid * 4; e < TI * NOUT; e += 256 * 4) {
            *(float4*)&wls[e] = *(const float4*)&wl[(size_t)it * NOUT + e];
            *(float4*)&wrs[e] = *(const float4*)&wr[(size_t)it * NOUT + e];
        }
        __syncthreads();

#pragma unroll
        for (int ii = 0; ii < TI; ++ii) {
            const float hv = hs[pt][ii];
            const float nv = ns[pt][ii];
#pragma unroll
            for (int j = 0; j < JPT; j += 4) {
                float4 wl4 = *(const float4*)&wls[ii * NOUT + o0 + j];
                float4 wr4 = *(const float4*)&wrs[ii * NOUT + o0 + j];
                acc[j + 0] += nv * wl4.x + hv * wr4.x;
                acc[j + 1] += nv * wl4.y + hv * wr4.y;
                acc[j + 2] += nv * wl4.z + hv * wr4.z;
                acc[j + 3] += nv * wl4.w + hv * wr4.w;
            }
        }
    }

    float* op = out + (size_t)(n0 + pt) * NOUT + o0;
#pragma unroll
    for (int j = 0; j < JPT; ++j) {
        float v = acc[j] + bias[o0 + j];
        op[j] = v > 0.f ? v : 0.f;
    }
}

// ---------------------------------------------------------------------------
// Head: per-graph max-pool over 512 points (32 ch) -> 32x32 MLP -> 32x3.
// One block (256 thr) per graph.
// ---------------------------------------------------------------------------
__global__ __launch_bounds__(256)
void head_kernel(const float* __restrict__ h3, const float* __restrict__ lw0,
                 const float* __restrict__ lb0, const float* __restrict__ lw1,
                 const float* __restrict__ lb1, float* __restrict__ out) {
    __shared__ float red[256];
    __shared__ float pooled[32];
    __shared__ float hid[32];
    const int g = blockIdx.x;
    const int t = threadIdx.x;
    const int c = t & 31;
    const int r = t >> 5;    // 0..7

    const float* hb = h3 + (size_t)g * P * 32;
    float m = -3.4e38f;
    for (int p = r; p < P; p += 8) m = fmaxf(m, hb[p * 32 + c]);
    red[t] = m;
    __syncthreads();
    if (r < 4) red[t] = fmaxf(red[t], red[t + 128]);
    __syncthreads();
    if (r < 2) red[t] = fmaxf(red[t], red[t + 64]);
    __syncthreads();
    if (r == 0) pooled[c] = fmaxf(red[t], red[t + 32]);
    __syncthreads();

    if (t < 32) {
        float a = lb0[t];
#pragma unroll
        for (int i = 0; i < 32; ++i) a += pooled[i] * lw0[i * 32 + t];
        hid[t] = a > 0.f ? a : 0.f;
    }
    __syncthreads();
    if (t < 3) {
        float a = lb1[t];
#pragma unroll
        for (int i = 0; i < 32; ++i) a += hid[i] * lw1[i * 3 + t];
        out[g * 3 + t] = a;
    }
}

// ---------------------------------------------------------------------------
extern "C" void kernel_launch(void* const* d_in, const int* in_sizes, int n_in,
                              void* d_out, int out_size, void* d_ws, size_t ws_size,
                              hipStream_t stream) {
    const float* x   = (const float*)d_in[0];
    const int*   coo = (const int*)  d_in[1];
    const float* wl0 = (const float*)d_in[2];
    const float* wr0 = (const float*)d_in[3];
    const float* b0  = (const float*)d_in[4];
    const float* wl1 = (const float*)d_in[5];
    const float* wr1 = (const float*)d_in[6];
    const float* b1  = (const float*)d_in[7];
    const float* wl2 = (const float*)d_in[8];
    const float* wr2 = (const float*)d_in[9];
    const float* b2  = (const float*)d_in[10];
    const float* lw0 = (const float*)d_in[11];
    const float* lb0 = (const float*)d_in[12];
    const float* lw1 = (const float*)d_in[13];
    const float* lb1 = (const float*)d_in[14];
    float* out = (float*)d_out;

    char* ws = (char*)d_ws;
    // Workspace layout (bytes):
    //   idx : NPTS*K*4            =  4,194,304
    //   nbr : NPTS*128*4          = 33,554,432
    //   h1  : NPTS*96*4           = 25,165,824
    //   h2  : NPTS*64*4           = 16,777,216
    //   h3  : NPTS*32*4           =  8,388,608   (total ~88 MB)
    int*   idx = (int*)ws;
    float* nbr = (float*)(ws + 4194304);
    float* h1  = (float*)(ws + 4194304 + 33554432);
    float* h2  = (float*)(ws + 4194304 + 33554432 + 25165824);
    float* h3  = (float*)(ws + 4194304 + 33554432 + 25165824 + 16777216);

    knn_kernel<<<G, P, 0, stream>>>(coo, idx);

    gather_mean_kernel<128><<<NPTS, 128, 0, stream>>>(x, idx, nbr);
    sage_kernel<128, 96><<<NPTS / 64, 256, 0, stream>>>(nbr, x, wl0, wr0, b0, h1);

    gather_mean_kernel<96><<<NPTS, 128, 0, stream>>>(h1, idx, nbr);
    sage_kernel<96, 64><<<NPTS / 64, 256, 0, stream>>>(nbr, h1, wl1, wr1, b1, h2);

    gather_mean_kernel<64><<<NPTS, 128, 0, stream>>>(h2, idx, nbr);
    sage_kernel<64, 32><<<NPTS / 64, 256, 0, stream>>>(nbr, h2, wl2, wr2, b2, h3);

    head_kernel<<<G, 256, 0, stream>>>(h3, lw0, lb0, lw1, lb1, out);
}

// Round 2
// 428.714 us; speedup vs baseline: 1.1610x; 1.1610x over previous
//
#include <hip/hip_runtime.h>

#define G 128
#define P 512
#define K 16
#define NPTS (G * P)   // 65536

// ---------------------------------------------------------------------------
// KNN v2: 4 threads per target. Grid = G*8 blocks, 256 threads.
// Block handles 64 targets; thread (sub, tgt) scans sources
// [sub*128, sub*128+128) keeping an exact top-16 of key=(d2<<9)|src
// (unique keys -> exact lax.top_k tie-breaking). Sub 0 merges the three
// foreign lists from LDS (fully-active wave 0).
// ---------------------------------------------------------------------------
__global__ __launch_bounds__(256)
void knn_kernel(const int* __restrict__ coo, int* __restrict__ idx_out) {
    __shared__ int sc[P];              // packed (x<<6)|y
    __shared__ unsigned mk[64][49];    // 48 foreign keys per target (+pad)
    const int b   = blockIdx.x;        // 0..1023
    const int g   = b >> 3;
    const int t0  = (b & 7) * 64;
    const int tid = threadIdx.x;
    const int tgt = tid & 63;
    const int sub = tid >> 6;          // wave id, uniform per wave

    for (int i = tid; i < P; i += 256) {
        const int* cp = coo + (size_t)(g * P + i) * 3;
        sc[i] = (cp[0] << 6) | cp[1];
    }
    __syncthreads();

    const int tg = t0 + tgt;           // target local index in graph
    const int pc = sc[tg];
    const int px = pc >> 6, py = pc & 63;

    unsigned best[K];
#pragma unroll
    for (int k = 0; k < K; ++k) best[k] = 0xFFFFFFFFu;
    unsigned worst = 0xFFFFFFFFu;
    int wi = 0;

    const int s0 = sub * 128;
    for (int j = 0; j < 128; ++j) {
        const int s = s0 + j;
        const int c = sc[s];
        const int dx = px - (c >> 6);
        const int dy = py - (c & 63);
        unsigned key = ((unsigned)(dx * dx + dy * dy) << 9) | (unsigned)s;
        if (s == tg) key = 0xFFFFFFFFu;           // loop=False (branchless)
        if (key < worst) {
            best[wi] = key;
            worst = best[0]; wi = 0;
#pragma unroll
            for (int k = 1; k < K; ++k)
                if (best[k] > worst) { worst = best[k]; wi = k; }
        }
    }

    if (sub != 0) {
#pragma unroll
        for (int k = 0; k < K; ++k) mk[tgt][(sub - 1) * 16 + k] = best[k];
    }
    __syncthreads();

    if (sub == 0) {
        for (int j = 0; j < 48; ++j) {
            const unsigned key = mk[tgt][j];
            if (key < worst) {
                best[wi] = key;
                worst = best[0]; wi = 0;
#pragma unroll
                for (int k = 1; k < K; ++k)
                    if (best[k] > worst) { worst = best[k]; wi = k; }
            }
        }
        int* op = idx_out + (size_t)(g * P + tg) * K;
#pragma unroll
        for (int k = 0; k < K; ++k) op[k] = (int)(best[k] & (unsigned)(P - 1));
    }
}

// ---------------------------------------------------------------------------
// Fused SAGE layer: out = relu(mean_nbr(h) @ wl + h @ wr + b)
// Block: 256 threads, 64 points. Per 32-channel i-tile:
//   stage h tile + gathered 16-neighbor mean into LDS (graph slab is L2-hot),
//   then FMA GEMM with weights via wave-uniform scalar loads (s_load path).
// ---------------------------------------------------------------------------
template <int NIN, int NOUT>
__global__ __launch_bounds__(256)
void sage_fused_kernel(const float* __restrict__ h, const int* __restrict__ idxg,
                       const float* __restrict__ wl, const float* __restrict__ wr,
                       const float* __restrict__ bias, float* __restrict__ out) {
    constexpr int TI  = 32;            // i-tile
    constexpr int JPT = NOUT / 4;      // outputs per thread

    __shared__ float hs[64][TI + 1];
    __shared__ float ms[64][TI + 1];
    __shared__ int   nb[64 * K];

    const int tid = threadIdx.x;
    const int n0  = blockIdx.x * 64;
    const int g   = n0 >> 9;
    const float* __restrict__ hg = h + (size_t)(g * P) * NIN;  // graph slab

    // neighbor indices for this block's 64 points (contiguous in idxg)
    for (int i = tid; i < 64 * K; i += 256) nb[i] = idxg[(size_t)n0 * K + i];

    const int pt = tid & 63;
    const int og = __builtin_amdgcn_readfirstlane(tid >> 6);  // wave-uniform
    const int o0 = og * JPT;
    const int r  = tid >> 2;           // staging: point
    const int c0 = (tid & 3) * 8;      // staging: 8 channels

    float acc[JPT];
#pragma unroll
    for (int j = 0; j < JPT; ++j) acc[j] = 0.f;

    for (int it = 0; it < NIN; it += TI) {
        __syncthreads();   // protect previous tile's LDS reads (and nb load)

        // stage h tile
        {
            const float* hp = h + (size_t)(n0 + r) * NIN + it + c0;
            float4 a0 = *(const float4*)hp;
            float4 a1 = *(const float4*)(hp + 4);
            hs[r][c0 + 0] = a0.x; hs[r][c0 + 1] = a0.y;
            hs[r][c0 + 2] = a0.z; hs[r][c0 + 3] = a0.w;
            hs[r][c0 + 4] = a1.x; hs[r][c0 + 5] = a1.y;
            hs[r][c0 + 6] = a1.z; hs[r][c0 + 7] = a1.w;
        }
        // gather 16-neighbor mean for this tile slice
        {
            float4 s0v = {0.f, 0.f, 0.f, 0.f};
            float4 s1v = {0.f, 0.f, 0.f, 0.f};
#pragma unroll 8
            for (int k = 0; k < K; ++k) {
                const float* q = hg + (size_t)nb[r * K + k] * NIN + it + c0;
                float4 q0 = *(const float4*)q;
                float4 q1 = *(const float4*)(q + 4);
                s0v.x += q0.x; s0v.y += q0.y; s0v.z += q0.z; s0v.w += q0.w;
                s1v.x += q1.x; s1v.y += q1.y; s1v.z += q1.z; s1v.w += q1.w;
            }
            const float sc16 = 1.0f / 16.0f;
            ms[r][c0 + 0] = s0v.x * sc16; ms[r][c0 + 1] = s0v.y * sc16;
            ms[r][c0 + 2] = s0v.z * sc16; ms[r][c0 + 3] = s0v.w * sc16;
            ms[r][c0 + 4] = s1v.x * sc16; ms[r][c0 + 5] = s1v.y * sc16;
            ms[r][c0 + 6] = s1v.z * sc16; ms[r][c0 + 7] = s1v.w * sc16;
        }
        __syncthreads();

#pragma unroll
        for (int ii = 0; ii < TI; ++ii) {
            const float hv = hs[pt][ii];
            const float nv = ms[pt][ii];
            const float* wlrow = wl + (size_t)(it + ii) * NOUT + o0;  // uniform
            const float* wrrow = wr + (size_t)(it + ii) * NOUT + o0;  // uniform
#pragma unroll
            for (int j = 0; j < JPT; ++j)
                acc[j] += nv * wlrow[j] + hv * wrrow[j];
        }
    }

    float* op = out + (size_t)(n0 + pt) * NOUT + o0;
#pragma unroll
    for (int j = 0; j < JPT; ++j) {
        float v = acc[j] + bias[o0 + j];
        op[j] = v > 0.f ? v : 0.f;
    }
}

// ---------------------------------------------------------------------------
// Head: per-graph max-pool over 512 points (32 ch) -> 32x32 MLP -> 32x3.
// ---------------------------------------------------------------------------
__global__ __launch_bounds__(256)
void head_kernel(const float* __restrict__ h3, const float* __restrict__ lw0,
                 const float* __restrict__ lb0, const float* __restrict__ lw1,
                 const float* __restrict__ lb1, float* __restrict__ out) {
    __shared__ float red[256];
    __shared__ float pooled[32];
    __shared__ float hid[32];
    const int g = blockIdx.x;
    const int t = threadIdx.x;
    const int c = t & 31;
    const int r = t >> 5;    // 0..7

    const float* hb = h3 + (size_t)g * P * 32;
    float m = -3.4e38f;
    for (int p = r; p < P; p += 8) m = fmaxf(m, hb[p * 32 + c]);
    red[t] = m;
    __syncthreads();
    if (r < 4) red[t] = fmaxf(red[t], red[t + 128]);
    __syncthreads();
    if (r < 2) red[t] = fmaxf(red[t], red[t + 64]);
    __syncthreads();
    if (r == 0) pooled[c] = fmaxf(red[t], red[t + 32]);
    __syncthreads();

    if (t < 32) {
        float a = lb0[t];
#pragma unroll
        for (int i = 0; i < 32; ++i) a += pooled[i] * lw0[i * 32 + t];
        hid[t] = a > 0.f ? a : 0.f;
    }
    __syncthreads();
    if (t < 3) {
        float a = lb1[t];
#pragma unroll
        for (int i = 0; i < 32; ++i) a += hid[i] * lw1[i * 3 + t];
        out[g * 3 + t] = a;
    }
}

// ---------------------------------------------------------------------------
extern "C" void kernel_launch(void* const* d_in, const int* in_sizes, int n_in,
                              void* d_out, int out_size, void* d_ws, size_t ws_size,
                              hipStream_t stream) {
    const float* x   = (const float*)d_in[0];
    const int*   coo = (const int*)  d_in[1];
    const float* wl0 = (const float*)d_in[2];
    const float* wr0 = (const float*)d_in[3];
    const float* b0  = (const float*)d_in[4];
    const float* wl1 = (const float*)d_in[5];
    const float* wr1 = (const float*)d_in[6];
    const float* b1  = (const float*)d_in[7];
    const float* wl2 = (const float*)d_in[8];
    const float* wr2 = (const float*)d_in[9];
    const float* b2  = (const float*)d_in[10];
    const float* lw0 = (const float*)d_in[11];
    const float* lb0 = (const float*)d_in[12];
    const float* lw1 = (const float*)d_in[13];
    const float* lb1 = (const float*)d_in[14];
    float* out = (float*)d_out;

    char* ws = (char*)d_ws;
    // Workspace layout (bytes):
    //   idx : NPTS*K*4  =  4,194,304
    //   h1  : NPTS*96*4 = 25,165,824
    //   h2  : NPTS*64*4 = 16,777,216
    //   h3  : NPTS*32*4 =  8,388,608   (total ~54 MB)
    int*   idx = (int*)ws;
    float* h1  = (float*)(ws + 4194304);
    float* h2  = (float*)(ws + 4194304 + 25165824);
    float* h3  = (float*)(ws + 4194304 + 25165824 + 16777216);

    knn_kernel<<<G * 8, 256, 0, stream>>>(coo, idx);

    sage_fused_kernel<128, 96><<<NPTS / 64, 256, 0, stream>>>(x,  idx, wl0, wr0, b0, h1);
    sage_fused_kernel< 96, 64><<<NPTS / 64, 256, 0, stream>>>(h1, idx, wl1, wr1, b1, h2);
    sage_fused_kernel< 64, 32><<<NPTS / 64, 256, 0, stream>>>(h2, idx, wl2, wr2, b2, h3);

    head_kernel<<<G, 256, 0, stream>>>(h3, lw0, lb0, lw1, lb1, out);
}

// Round 3
// 414.775 us; speedup vs baseline: 1.2000x; 1.0336x over previous
//
#include <hip/hip_runtime.h>

#define G 128
#define P 512
#define K 16
#define NPTS (G * P)   // 65536

typedef _Float16 half8 __attribute__((ext_vector_type(8)));
typedef float    floatx4 __attribute__((ext_vector_type(4)));

// ---------------------------------------------------------------------------
// KNN v3: histogram threshold select. 256 targets/block, 1 thread/target.
// Exact: selects all d2 < T plus first (16-c1) by index at d2 == T, which is
// the 16 smallest (d2<<9)|idx keys == lax.top_k tie-breaking.
// ---------------------------------------------------------------------------
__global__ __launch_bounds__(256)
void knn_kernel(const int* __restrict__ coo, int* __restrict__ idx_out) {
    __shared__ int sc[P];                       // packed (x<<6)|y
    __shared__ unsigned char hist[256 * 132];   // 128 u8 bins + 4 pad per target
    const int b  = blockIdx.x;                  // 0..255
    const int g  = b >> 1;
    const int t0 = (b & 1) * 256;
    const int t  = threadIdx.x;

    for (int i = t; i < P; i += 256) {
        const int* cp = coo + (size_t)(g * P + i) * 3;
        sc[i] = (cp[0] << 6) | cp[1];
    }
    {
        unsigned* h32 = (unsigned*)hist;
        for (int i = t; i < 256 * 132 / 4; i += 256) h32[i] = 0u;
    }
    __syncthreads();

    const int tg = t0 + t;
    const int pc = sc[tg];
    const int px = pc >> 6, py = pc & 63;
    unsigned char* hrow = hist + t * 132;

    // pass 1: histogram of d2 (clamped to <128; larger never matters here)
    for (int s = 0; s < P; ++s) {
        const int c = sc[s];                    // broadcast read
        const int dx = px - (c >> 6), dy = py - (c & 63);
        const int d2 = dx * dx + dy * dy;
        if (d2 < 128 && s != tg) {
            int v = hrow[d2] + 1;
            hrow[d2] = (unsigned char)(v > 255 ? 255 : v);  // saturate (safe)
        }
    }
    // threshold scan (own row only, no sync needed)
    int Td = -1, c1 = 0, cum = 0;
    const unsigned* hrow32 = (const unsigned*)hrow;
    for (int w = 0; w < 32; ++w) {
        const unsigned u = hrow32[w];
#pragma unroll
        for (int q = 0; q < 4; ++q) {
            const int c = (u >> (8 * q)) & 255;
            if (Td < 0 && cum + c >= 16) { Td = w * 4 + q; c1 = cum; }
            cum += c;
        }
    }

    int* op = idx_out + (size_t)(g * P + tg) * K;
    if (Td >= 0) {
        const int quota = 16 - c1;
        int slot = 0, eq = 0;
        for (int s = 0; s < P; ++s) {
            if (s == tg) continue;
            const int c = sc[s];
            const int dx = px - (c >> 6), dy = py - (c & 63);
            const int d2 = dx * dx + dy * dy;
            if (d2 < Td) op[slot++] = s;
            else if (d2 == Td) { if (eq < quota) op[slot++] = s; eq++; }
        }
    } else {
        // exact fallback: <16 points within d2<128 (effectively never)
        unsigned best[K];
#pragma unroll
        for (int k = 0; k < K; ++k) best[k] = 0xFFFFFFFFu;
        unsigned worst = 0xFFFFFFFFu; int wi = 0;
        for (int s = 0; s < P; ++s) {
            if (s == tg) continue;
            const int c = sc[s];
            const int dx = px - (c >> 6), dy = py - (c & 63);
            const unsigned key = ((unsigned)(dx * dx + dy * dy) << 9) | (unsigned)s;
            if (key < worst) {
                best[wi] = key; worst = best[0]; wi = 0;
#pragma unroll
                for (int k = 1; k < K; ++k)
                    if (best[k] > worst) { worst = best[k]; wi = k; }
            }
        }
#pragma unroll
        for (int k = 0; k < K; ++k) op[k] = (int)(best[k] & (unsigned)(P - 1));
    }
}

// ---------------------------------------------------------------------------
// prep: convert [wl;wr] fp32 -> fp16 in MFMA B-fragment layout.
// frag (ntile,kt): lane l holds B[kt*32+(l>>4)*8+j][ntile*16+(l&15)], j=0..7.
// ---------------------------------------------------------------------------
template <int NT, int KT, int NIN, int NOUT>
__global__ __launch_bounds__(256)
void prep_kernel(const float* __restrict__ wl, const float* __restrict__ wr,
                 _Float16* __restrict__ wf) {
    const int e = blockIdx.x * 256 + threadIdx.x;
    if (e >= NT * KT * 512) return;
    const int fr   = e >> 9;            // ntile*KT + kt
    const int lane = (e >> 3) & 63;
    const int j    = e & 7;
    const int ntile = fr / KT;
    const int kt    = fr - ntile * KT;
    const int k = kt * 32 + ((lane >> 4) << 3) + j;
    const int n = ntile * 16 + (lane & 15);
    const float v = (k < NIN) ? wl[k * NOUT + n] : wr[(k - NIN) * NOUT + n];
    wf[e] = (_Float16)v;
}

// ---------------------------------------------------------------------------
// Fused SAGE: out = relu([mean_nbr(h) | h] @ [wl;wr] + b) via f16 MFMA.
// Block: 256 thr / 4 waves, 128 points. Wave w: M-half mh=w&1 (64 pts =
// 4 M-tiles), N-half nh=w>>1 (NH = NOUT/32 N-tiles, B frags in VGPRs).
// A staged fp16 in LDS, XOR-swizzled 8-half groups (<=2-way bank conflicts).
// ---------------------------------------------------------------------------
template <bool FIN32, int NIN, int NOUT, bool FOUT16>
__global__ __launch_bounds__(256)
void sage_kernel(const void* __restrict__ hin, const int* __restrict__ idxg,
                 const _Float16* __restrict__ wf, const float* __restrict__ bias,
                 void* __restrict__ hout) {
    constexpr int KC = 2 * NIN;       // concat K
    constexpr int KT = KC / 32;       // MFMA k-steps
    constexpr int NH = NOUT / 32;     // N-tiles per wave
    constexpr int CH = NIN / 16;      // 8-ch chunks per half

    __shared__ _Float16 As[128 * KC];
    __shared__ int nb[128 * K];

    const int tid = threadIdx.x;
    const int n0  = blockIdx.x * 128;
    const int g   = n0 >> 9;

    { const int* src = idxg + (size_t)n0 * K;
      for (int i = tid; i < 128 * K; i += 256) nb[i] = src[i]; }
    __syncthreads();

    const int pt   = tid >> 1;
    const int half = tid & 1;
    const int ch0  = half * (NIN / 2);
    const int xs   = pt & 7;

    const float*    hgf = (const float*)hin    + (size_t)(g * P) * NIN;
    const _Float16* hgh = (const _Float16*)hin + (size_t)(g * P) * NIN;

    // ---- phase 1: neighbor mean (fp32 accum) + root h, staged fp16 ----
    for (int c = 0; c < CH; ++c) {
        const int ch = ch0 + c * 8;
        float s0=0,s1=0,s2=0,s3=0,s4=0,s5=0,s6=0,s7=0;
#pragma unroll
        for (int k = 0; k < K; ++k) {
            const int nn = nb[pt * K + k];
            if constexpr (FIN32) {
                const float* q = hgf + (size_t)nn * NIN + ch;
                const float4 a  = *(const float4*)q;
                const float4 bq = *(const float4*)(q + 4);
                s0+=a.x; s1+=a.y; s2+=a.z; s3+=a.w;
                s4+=bq.x; s5+=bq.y; s6+=bq.z; s7+=bq.w;
            } else {
                const half8 v = *(const half8*)(hgh + (size_t)nn * NIN + ch);
                s0+=(float)v[0]; s1+=(float)v[1]; s2+=(float)v[2]; s3+=(float)v[3];
                s4+=(float)v[4]; s5+=(float)v[5]; s6+=(float)v[6]; s7+=(float)v[7];
            }
        }
        half8 m;
        m[0]=(_Float16)(s0*0.0625f); m[1]=(_Float16)(s1*0.0625f);
        m[2]=(_Float16)(s2*0.0625f); m[3]=(_Float16)(s3*0.0625f);
        m[4]=(_Float16)(s4*0.0625f); m[5]=(_Float16)(s5*0.0625f);
        m[6]=(_Float16)(s6*0.0625f); m[7]=(_Float16)(s7*0.0625f);
        const int gl = ch >> 3;
        *(half8*)&As[pt * KC + ((gl ^ xs) << 3)] = m;
    }
    for (int c = 0; c < CH; ++c) {
        const int ch = ch0 + c * 8;
        half8 m;
        if constexpr (FIN32) {
            const float* q = (const float*)hin + (size_t)(n0 + pt) * NIN + ch;
            const float4 a  = *(const float4*)q;
            const float4 bq = *(const float4*)(q + 4);
            m[0]=(_Float16)a.x;  m[1]=(_Float16)a.y;
            m[2]=(_Float16)a.z;  m[3]=(_Float16)a.w;
            m[4]=(_Float16)bq.x; m[5]=(_Float16)bq.y;
            m[6]=(_Float16)bq.z; m[7]=(_Float16)bq.w;
        } else {
            m = *(const half8*)((const _Float16*)hin + (size_t)(n0 + pt) * NIN + ch);
        }
        const int gl = (NIN >> 3) + (ch >> 3);
        *(half8*)&As[pt * KC + ((gl ^ xs) << 3)] = m;
    }

    // ---- B fragments + bias into registers ----
    const int l  = tid & 63;
    const int wv = tid >> 6;
    const int mh = wv & 1;
    const int nh = wv >> 1;
    const int lm = l & 15, lq = l >> 4;

    half8 bf[NH][KT];
#pragma unroll
    for (int nt = 0; nt < NH; ++nt)
#pragma unroll
        for (int kt = 0; kt < KT; ++kt) {
            const int ng = nh * NH + nt;
            bf[nt][kt] = *(const half8*)(wf + ((size_t)(ng * KT + kt) * 64 + l) * 8);
        }
    float bs[NH];
#pragma unroll
    for (int nt = 0; nt < NH; ++nt)
        bs[nt] = bias[nh * (NOUT / 2) + nt * 16 + lm];

    __syncthreads();

    // ---- phase 2: MFMA ----
    floatx4 acc[4][NH];
#pragma unroll
    for (int mt = 0; mt < 4; ++mt)
#pragma unroll
        for (int nt = 0; nt < NH; ++nt) {
            floatx4 z = {0.f, 0.f, 0.f, 0.f};
            acc[mt][nt] = z;
        }
#pragma unroll
    for (int kt = 0; kt < KT; ++kt) {
#pragma unroll
        for (int mt = 0; mt < 4; ++mt) {
            const int row  = mh * 64 + mt * 16 + lm;
            const int gidx = kt * 4 + lq;
            const half8 a = *(const half8*)&As[row * KC + ((gidx ^ (row & 7)) << 3)];
#pragma unroll
            for (int nt = 0; nt < NH; ++nt)
                acc[mt][nt] = __builtin_amdgcn_mfma_f32_16x16x32_f16(
                    a, bf[nt][kt], acc[mt][nt], 0, 0, 0);
        }
    }

    // ---- epilogue: bias + relu, store ----
#pragma unroll
    for (int mt = 0; mt < 4; ++mt)
#pragma unroll
        for (int nt = 0; nt < NH; ++nt) {
            const int n = nh * (NOUT / 2) + nt * 16 + lm;
#pragma unroll
            for (int r = 0; r < 4; ++r) {
                const int p = n0 + mh * 64 + mt * 16 + lq * 4 + r;
                float v = acc[mt][nt][r] + bs[nt];
                v = v > 0.f ? v : 0.f;
                if constexpr (FOUT16)
                    ((_Float16*)hout)[(size_t)p * NOUT + n] = (_Float16)v;
                else
                    ((float*)hout)[(size_t)p * NOUT + n] = v;
            }
        }
}

// ---------------------------------------------------------------------------
// Head: per-graph max-pool (512 pts x 32 ch, fp32) -> 32x32 MLP -> 32x3.
// ---------------------------------------------------------------------------
__global__ __launch_bounds__(256)
void head_kernel(const float* __restrict__ h3, const float* __restrict__ lw0,
                 const float* __restrict__ lb0, const float* __restrict__ lw1,
                 const float* __restrict__ lb1, float* __restrict__ out) {
    __shared__ float red[256];
    __shared__ float pooled[32];
    __shared__ float hid[32];
    const int g = blockIdx.x;
    const int t = threadIdx.x;
    const int c = t & 31;
    const int r = t >> 5;

    const float* hb = h3 + (size_t)g * P * 32;
    float m = -3.4e38f;
    for (int p = r; p < P; p += 8) m = fmaxf(m, hb[p * 32 + c]);
    red[t] = m;
    __syncthreads();
    if (r < 4) red[t] = fmaxf(red[t], red[t + 128]);
    __syncthreads();
    if (r < 2) red[t] = fmaxf(red[t], red[t + 64]);
    __syncthreads();
    if (r == 0) pooled[c] = fmaxf(red[t], red[t + 32]);
    __syncthreads();

    if (t < 32) {
        float a = lb0[t];
#pragma unroll
        for (int i = 0; i < 32; ++i) a += pooled[i] * lw0[i * 32 + t];
        hid[t] = a > 0.f ? a : 0.f;
    }
    __syncthreads();
    if (t < 3) {
        float a = lb1[t];
#pragma unroll
        for (int i = 0; i < 32; ++i) a += hid[i] * lw1[i * 3 + t];
        out[g * 3 + t] = a;
    }
}

// ---------------------------------------------------------------------------
extern "C" void kernel_launch(void* const* d_in, const int* in_sizes, int n_in,
                              void* d_out, int out_size, void* d_ws, size_t ws_size,
                              hipStream_t stream) {
    const float* x   = (const float*)d_in[0];
    const int*   coo = (const int*)  d_in[1];
    const float* wl0 = (const float*)d_in[2];
    const float* wr0 = (const float*)d_in[3];
    const float* b0  = (const float*)d_in[4];
    const float* wl1 = (const float*)d_in[5];
    const float* wr1 = (const float*)d_in[6];
    const float* b1  = (const float*)d_in[7];
    const float* wl2 = (const float*)d_in[8];
    const float* wr2 = (const float*)d_in[9];
    const float* b2  = (const float*)d_in[10];
    const float* lw0 = (const float*)d_in[11];
    const float* lb0 = (const float*)d_in[12];
    const float* lw1 = (const float*)d_in[13];
    const float* lb1 = (const float*)d_in[14];
    float* out = (float*)d_out;

    char* ws = (char*)d_ws;
    // Workspace (bytes):
    //   wf0 fp16 frag weights : 49,152   @ 0
    //   wf1                   : 24,576   @ 49,152
    //   wf2                   :  8,192   @ 73,728
    //   idx int               : 4,194,304 @ 81,920
    //   h1 fp16 (65536x96)    : 12,582,912 @ 4,276,224
    //   h2 fp16 (65536x64)    :  8,388,608 @ 16,859,136
    //   h3 fp32 (65536x32)    :  8,388,608 @ 25,247,744   (end 33,636,352)
    _Float16* wf0 = (_Float16*)(ws + 0);
    _Float16* wf1 = (_Float16*)(ws + 49152);
    _Float16* wf2 = (_Float16*)(ws + 73728);
    int*      idx = (int*)     (ws + 81920);
    _Float16* h1  = (_Float16*)(ws + 4276224);
    _Float16* h2  = (_Float16*)(ws + 16859136);
    float*    h3  = (float*)   (ws + 25247744);

    prep_kernel<6, 8, 128, 96><<<96, 256, 0, stream>>>(wl0, wr0, wf0);
    prep_kernel<4, 6,  96, 64><<<48, 256, 0, stream>>>(wl1, wr1, wf1);
    prep_kernel<2, 4,  64, 32><<<16, 256, 0, stream>>>(wl2, wr2, wf2);

    knn_kernel<<<NPTS / 256, 256, 0, stream>>>(coo, idx);

    sage_kernel<true,  128, 96, true ><<<NPTS / 128, 256, 0, stream>>>(x,  idx, wf0, b0, h1);
    sage_kernel<false,  96, 64, true ><<<NPTS / 128, 256, 0, stream>>>(h1, idx, wf1, b1, h2);
    sage_kernel<false,  64, 32, false><<<NPTS / 128, 256, 0, stream>>>(h2, idx, wf2, b2, h3);

    head_kernel<<<G, 256, 0, stream>>>(h3, lw0, lb0, lw1, lb1, out);
}

// Round 4
// 270.675 us; speedup vs baseline: 1.8388x; 1.5324x over previous
//
#include <hip/hip_runtime.h>

#define G 128
#define P 512
#define K 16
#define NPTS (G * P)   // 65536

typedef _Float16 half8 __attribute__((ext_vector_type(8)));
typedef float    floatx4 __attribute__((ext_vector_type(4)));

__device__ __forceinline__ unsigned umaxu(unsigned a, unsigned b) { return a > b ? a : b; }

// ---------------------------------------------------------------------------
// KNN v4: 4 subs x 64 targets per 256-thr block, grid G*8.
// Branchless top-16 maintenance, NO dynamic register indexing:
//   best[] holds unique values (sentinels 0xFFFFFFF0+k >> any real key);
//   rk = min(key, worst); best[k] = (best[k]==worst) ? rk : best[k];
//   worst = max-tree(best).
// Exact lax.top_k((d2<<9)|idx) semantics; float math is exact (d2 < 2^24).
// ---------------------------------------------------------------------------
__global__ __launch_bounds__(256)
void knn_kernel(const int* __restrict__ coo, int* __restrict__ idx_out) {
    __shared__ float2 sxy[P];
    __shared__ unsigned mk[64][49];    // 48 foreign keys + pad (stride 49: odd)
    const int b   = blockIdx.x;        // 0..1023
    const int g   = b >> 3;
    const int t0  = (b & 7) * 64;
    const int tid = threadIdx.x;
    const int tgt = tid & 63;
    const int sub = tid >> 6;          // wave-uniform

    for (int i = tid; i < P; i += 256) {
        const int* cp = coo + (size_t)(g * P + i) * 3;
        sxy[i] = make_float2((float)cp[0], (float)cp[1]);
    }
    __syncthreads();

    const int tg = t0 + tgt;
    const float px = sxy[tg].x, py = sxy[tg].y;

    unsigned best[K];
#pragma unroll
    for (int k = 0; k < K; ++k) best[k] = 0xFFFFFFF0u + k;   // unique sentinels
    unsigned worst = 0xFFFFFFFFu;

    const int s0 = sub * 128;
    for (int j = 0; j < 128; ++j) {
        const int s = s0 + j;
        const float2 c = sxy[s];                  // uniform addr -> broadcast
        const float dx = px - c.x, dy = py - c.y;
        const float d2f = fmaf(dx, dx, dy * dy);  // exact integer value
        unsigned key = ((unsigned)(int)d2f << 9) | (unsigned)s;
        if (s == tg) key = 0xFFFFFFFFu;           // loop=False (cndmask)
        const unsigned rk = key < worst ? key : worst;
#pragma unroll
        for (int k = 0; k < K; ++k) best[k] = (best[k] == worst) ? rk : best[k];
        unsigned m0 = umaxu(best[0], best[1]),  m1 = umaxu(best[2], best[3]);
        unsigned m2 = umaxu(best[4], best[5]),  m3 = umaxu(best[6], best[7]);
        unsigned m4 = umaxu(best[8], best[9]),  m5 = umaxu(best[10], best[11]);
        unsigned m6 = umaxu(best[12], best[13]), m7 = umaxu(best[14], best[15]);
        m0 = umaxu(m0, m1); m2 = umaxu(m2, m3); m4 = umaxu(m4, m5); m6 = umaxu(m6, m7);
        worst = umaxu(umaxu(m0, m2), umaxu(m4, m6));
    }

    if (sub != 0) {
#pragma unroll
        for (int k = 0; k < K; ++k) mk[tgt][(sub - 1) * 16 + k] = best[k];
    }
    __syncthreads();

    if (sub == 0) {
        for (int j = 0; j < 48; ++j) {
            const unsigned key = mk[tgt][j];
            const unsigned rk = key < worst ? key : worst;
#pragma unroll
            for (int k = 0; k < K; ++k) best[k] = (best[k] == worst) ? rk : best[k];
            unsigned m0 = umaxu(best[0], best[1]),  m1 = umaxu(best[2], best[3]);
            unsigned m2 = umaxu(best[4], best[5]),  m3 = umaxu(best[6], best[7]);
            unsigned m4 = umaxu(best[8], best[9]),  m5 = umaxu(best[10], best[11]);
            unsigned m6 = umaxu(best[12], best[13]), m7 = umaxu(best[14], best[15]);
            m0 = umaxu(m0, m1); m2 = umaxu(m2, m3); m4 = umaxu(m4, m5); m6 = umaxu(m6, m7);
            worst = umaxu(umaxu(m0, m2), umaxu(m4, m6));
        }
        int* op = idx_out + (size_t)(g * P + tg) * K;
#pragma unroll
        for (int k = 0; k < K; ++k) op[k] = (int)(best[k] & (unsigned)(P - 1));
    }
}

// ---------------------------------------------------------------------------
// cvt: x fp32 -> fp16, 8 elements/thread.
// ---------------------------------------------------------------------------
__global__ __launch_bounds__(256)
void cvt_kernel(const float* __restrict__ x, _Float16* __restrict__ x16, int n8) {
    const int i = blockIdx.x * 256 + threadIdx.x;
    if (i >= n8) return;
    const float4* p = (const float4*)(x + (size_t)i * 8);
    const float4 a = p[0], bq = p[1];
    half8 o;
    o[0] = (_Float16)a.x;  o[1] = (_Float16)a.y;
    o[2] = (_Float16)a.z;  o[3] = (_Float16)a.w;
    o[4] = (_Float16)bq.x; o[5] = (_Float16)bq.y;
    o[6] = (_Float16)bq.z; o[7] = (_Float16)bq.w;
    *(half8*)(x16 + (size_t)i * 8) = o;
}

// ---------------------------------------------------------------------------
// prep: [wl;wr] fp32 -> fp16 MFMA B-fragment layout.
// frag (ntile,kt): lane l holds B[kt*32+(l>>4)*8+j][ntile*16+(l&15)], j=0..7.
// ---------------------------------------------------------------------------
template <int NT, int KT, int NIN, int NOUT>
__global__ __launch_bounds__(256)
void prep_kernel(const float* __restrict__ wl, const float* __restrict__ wr,
                 _Float16* __restrict__ wf) {
    const int e = blockIdx.x * 256 + threadIdx.x;
    if (e >= NT * KT * 512) return;
    const int fr   = e >> 9;
    const int lane = (e >> 3) & 63;
    const int j    = e & 7;
    const int ntile = fr / KT;
    const int kt    = fr - ntile * KT;
    const int k = kt * 32 + ((lane >> 4) << 3) + j;
    const int n = ntile * 16 + (lane & 15);
    const float v = (k < NIN) ? wl[k * NOUT + n] : wr[(k - NIN) * NOUT + n];
    wf[e] = (_Float16)v;
}

// ---------------------------------------------------------------------------
// Fused SAGE: out = relu([mean_nbr(h) | h] @ [wl;wr] + b), f16 MFMA.
// Block: 256 thr / 4 waves, 64 points (LDS 64*KC fp16 <= 32 KB -> 5 blk/CU).
// Phase 1: 4 lanes per point; lane (pt,q) gathers contiguous 64B rows
//   (q*8 channel offset within 32-ch chunks), fp32 accumulate, store fp16
//   into XOR-swizzled A (bijective per row -> min-conflict b128 access).
// Phase 2: wave (mh,nh): 2 M-tiles x NH N-tiles; B frags from L2-hot global.
// ---------------------------------------------------------------------------
template <int NIN, int NOUT, bool FOUT16>
__global__ __launch_bounds__(256)
void sage_kernel(const _Float16* __restrict__ hin, const int* __restrict__ idxg,
                 const _Float16* __restrict__ wf, const float* __restrict__ bias,
                 void* __restrict__ hout) {
    constexpr int KC  = 2 * NIN;      // concat K
    constexpr int KT  = KC / 32;      // MFMA k-steps
    constexpr int NH  = NOUT / 32;    // N-tiles per wave
    constexpr int CH4 = NIN / 32;     // 32-ch chunks per q-lane

    __shared__ _Float16 As[64 * KC];

    const int tid = threadIdx.x;
    const int n0  = blockIdx.x * 64;
    const int g   = n0 >> 9;
    const _Float16* __restrict__ hg = hin + (size_t)(g * P) * NIN;

    const int pt = tid >> 2;
    const int q  = tid & 3;
    const int xs = pt & 7;

    // 16 neighbor indices -> registers (L1-hot, 4x redundant)
    const int4* ip = (const int4*)(idxg + (size_t)(n0 + pt) * K);
    const int4 na = ip[0], nb4 = ip[1], nc = ip[2], nd = ip[3];
    const int nn[16] = {na.x, na.y, na.z, na.w, nb4.x, nb4.y, nb4.z, nb4.w,
                        nc.x, nc.y, nc.z, nc.w, nd.x, nd.y, nd.z, nd.w};

#pragma unroll
    for (int c = 0; c < CH4; ++c) {
        const int ch = c * 32 + q * 8;
        float s[8] = {0.f, 0.f, 0.f, 0.f, 0.f, 0.f, 0.f, 0.f};
#pragma unroll
        for (int k = 0; k < K; ++k) {
            const half8 v = *(const half8*)(hg + (size_t)nn[k] * NIN + ch);
#pragma unroll
            for (int e = 0; e < 8; ++e) s[e] += (float)v[e];
        }
        half8 m;
#pragma unroll
        for (int e = 0; e < 8; ++e) m[e] = (_Float16)(s[e] * 0.0625f);
        const int gl = (c * 4 + q) ^ xs;
        *(half8*)&As[pt * KC + gl * 8] = m;
        // root h
        const half8 rv = *(const half8*)(hin + (size_t)(n0 + pt) * NIN + ch);
        const int gr = (NIN / 8 + c * 4 + q) ^ xs;
        *(half8*)&As[pt * KC + gr * 8] = rv;
    }

    const int l  = tid & 63;
    const int wv = tid >> 6;
    const int mh = wv & 1;
    const int nh = wv >> 1;
    const int lm = l & 15, lq = l >> 4;

    float bs[NH];
#pragma unroll
    for (int nt = 0; nt < NH; ++nt)
        bs[nt] = bias[nh * (NOUT / 2) + nt * 16 + lm];

    __syncthreads();

    floatx4 acc[2][NH];
#pragma unroll
    for (int mt = 0; mt < 2; ++mt)
#pragma unroll
        for (int nt = 0; nt < NH; ++nt) {
            floatx4 z = {0.f, 0.f, 0.f, 0.f};
            acc[mt][nt] = z;
        }

#pragma unroll
    for (int kt = 0; kt < KT; ++kt) {
        half8 bfr[NH];
#pragma unroll
        for (int nt = 0; nt < NH; ++nt) {
            const int ng = nh * NH + nt;
            bfr[nt] = *(const half8*)(wf + ((size_t)(ng * KT + kt) * 64 + l) * 8);
        }
#pragma unroll
        for (int mt = 0; mt < 2; ++mt) {
            const int row = mh * 32 + mt * 16 + lm;
            const int gl  = (kt * 4 + lq) ^ (row & 7);
            const half8 a = *(const half8*)&As[row * KC + gl * 8];
#pragma unroll
            for (int nt = 0; nt < NH; ++nt)
                acc[mt][nt] = __builtin_amdgcn_mfma_f32_16x16x32_f16(
                    a, bfr[nt], acc[mt][nt], 0, 0, 0);
        }
    }

#pragma unroll
    for (int mt = 0; mt < 2; ++mt)
#pragma unroll
        for (int nt = 0; nt < NH; ++nt) {
            const int n = nh * (NOUT / 2) + nt * 16 + lm;
#pragma unroll
            for (int r = 0; r < 4; ++r) {
                const int p = n0 + mh * 32 + mt * 16 + lq * 4 + r;
                float v = acc[mt][nt][r] + bs[nt];
                v = v > 0.f ? v : 0.f;
                if constexpr (FOUT16)
                    ((_Float16*)hout)[(size_t)p * NOUT + n] = (_Float16)v;
                else
                    ((float*)hout)[(size_t)p * NOUT + n] = v;
            }
        }
}

// ---------------------------------------------------------------------------
// Head: per-graph max-pool (512 x 32, fp32) -> 32x32 MLP -> 32x3.
// ---------------------------------------------------------------------------
__global__ __launch_bounds__(256)
void head_kernel(const float* __restrict__ h3, const float* __restrict__ lw0,
                 const float* __restrict__ lb0, const float* __restrict__ lw1,
                 const float* __restrict__ lb1, float* __restrict__ out) {
    __shared__ float red[256];
    __shared__ float pooled[32];
    __shared__ float hid[32];
    const int g = blockIdx.x;
    const int t = threadIdx.x;
    const int c = t & 31;
    const int r = t >> 5;

    const float* hb = h3 + (size_t)g * P * 32;
    float m = -3.4e38f;
    for (int p = r; p < P; p += 8) m = fmaxf(m, hb[p * 32 + c]);
    red[t] = m;
    __syncthreads();
    if (r < 4) red[t] = fmaxf(red[t], red[t + 128]);
    __syncthreads();
    if (r < 2) red[t] = fmaxf(red[t], red[t + 64]);
    __syncthreads();
    if (r == 0) pooled[c] = fmaxf(red[t], red[t + 32]);
    __syncthreads();

    if (t < 32) {
        float a = lb0[t];
#pragma unroll
        for (int i = 0; i < 32; ++i) a += pooled[i] * lw0[i * 32 + t];
        hid[t] = a > 0.f ? a : 0.f;
    }
    __syncthreads();
    if (t < 3) {
        float a = lb1[t];
#pragma unroll
        for (int i = 0; i < 32; ++i) a += hid[i] * lw1[i * 3 + t];
        out[g * 3 + t] = a;
    }
}

// ---------------------------------------------------------------------------
extern "C" void kernel_launch(void* const* d_in, const int* in_sizes, int n_in,
                              void* d_out, int out_size, void* d_ws, size_t ws_size,
                              hipStream_t stream) {
    const float* x   = (const float*)d_in[0];
    const int*   coo = (const int*)  d_in[1];
    const float* wl0 = (const float*)d_in[2];
    const float* wr0 = (const float*)d_in[3];
    const float* b0  = (const float*)d_in[4];
    const float* wl1 = (const float*)d_in[5];
    const float* wr1 = (const float*)d_in[6];
    const float* b1  = (const float*)d_in[7];
    const float* wl2 = (const float*)d_in[8];
    const float* wr2 = (const float*)d_in[9];
    const float* b2  = (const float*)d_in[10];
    const float* lw0 = (const float*)d_in[11];
    const float* lb0 = (const float*)d_in[12];
    const float* lw1 = (const float*)d_in[13];
    const float* lb1 = (const float*)d_in[14];
    float* out = (float*)d_out;

    char* ws = (char*)d_ws;
    // Workspace (bytes):
    //   wf0 : 49,152      @ 0
    //   wf1 : 24,576      @ 49,152
    //   wf2 :  8,192      @ 73,728
    //   idx :  4,194,304  @ 81,920
    //   x16 : 16,777,216  @ 4,276,224   (65536 x 128 fp16)
    //   h1  : 12,582,912  @ 21,053,440  (fp16)
    //   h2  :  8,388,608  @ 33,636,352  (fp16)
    //   h3  :  8,388,608  @ 42,024,960  (fp32)  end ~50.4 MB
    _Float16* wf0 = (_Float16*)(ws + 0);
    _Float16* wf1 = (_Float16*)(ws + 49152);
    _Float16* wf2 = (_Float16*)(ws + 73728);
    int*      idx = (int*)     (ws + 81920);
    _Float16* x16 = (_Float16*)(ws + 4276224);
    _Float16* h1  = (_Float16*)(ws + 21053440);
    _Float16* h2  = (_Float16*)(ws + 33636352);
    float*    h3  = (float*)   (ws + 42024960);

    prep_kernel<6, 8, 128, 96><<<96, 256, 0, stream>>>(wl0, wr0, wf0);
    prep_kernel<4, 6,  96, 64><<<48, 256, 0, stream>>>(wl1, wr1, wf1);
    prep_kernel<2, 4,  64, 32><<<16, 256, 0, stream>>>(wl2, wr2, wf2);

    cvt_kernel<<<4096, 256, 0, stream>>>(x, x16, NPTS * 128 / 8);
    knn_kernel<<<G * 8, 256, 0, stream>>>(coo, idx);

    sage_kernel<128, 96, true ><<<NPTS / 64, 256, 0, stream>>>(x16, idx, wf0, b0, h1);
    sage_kernel< 96, 64, true ><<<NPTS / 64, 256, 0, stream>>>(h1,  idx, wf1, b1, h2);
    sage_kernel< 64, 32, false><<<NPTS / 64, 256, 0, stream>>>(h2,  idx, wf2, b2, h3);

    head_kernel<<<G, 256, 0, stream>>>(h3, lw0, lb0, lw1, lb1, out);
}

// Round 5
// 236.187 us; speedup vs baseline: 2.1073x; 1.1460x over previous
//
#include <hip/hip_runtime.h>

#define G 128
#define P 512
#define K 16
#define NPTS (G * P)   // 65536

typedef _Float16 half8 __attribute__((ext_vector_type(8)));
typedef float    floatx4 __attribute__((ext_vector_type(4)));

// ---------------------------------------------------------------------------
// Sorted-insertion of one key into ascending best[16]: 2 ops/slot, branchless,
// no dynamic indexing. After the chain, `key` holds the displaced max.
// ---------------------------------------------------------------------------
__device__ __forceinline__ void chain_insert(unsigned best[K], unsigned key) {
#pragma unroll
    for (int k = 0; k < K; ++k) {
        const unsigned bk = best[k];
        const unsigned lo = bk < key ? bk : key;
        key = bk < key ? key : bk;
        best[k] = lo;
    }
}

__device__ __forceinline__ void merge16(const unsigned* __restrict__ src,
                                        unsigned best[K]) {
    for (int j = 0; j < K; ++j) chain_insert(best, src[j]);
}

// ---------------------------------------------------------------------------
// KNN v5: 8 subs x 64 targets per 512-thr block, grid G*8 (32 waves/CU).
// Each sub scans 64 candidates with the insertion chain (~40 VALU/cand);
// 3-stage pairwise merge through LDS (stride 17 -> conflict-free).
// Exact lax.top_k((d2<<9)|idx): key=(d2*512+s) computed exactly in fp32.
// ---------------------------------------------------------------------------
__global__ __launch_bounds__(512)
void knn_kernel(const int* __restrict__ coo, int* __restrict__ idx_out) {
    __shared__ float2 sxy[P];
    __shared__ unsigned mk[4][64][17];
    const int b   = blockIdx.x;        // 0..1023
    const int g   = b >> 3;
    const int t0  = (b & 7) * 64;
    const int tid = threadIdx.x;
    const int tgt = tid & 63;
    const int sub = tid >> 6;          // 0..7, wave-uniform

    for (int i = tid; i < P; i += 512) {
        const int* cp = coo + (size_t)(g * P + i) * 3;
        sxy[i] = make_float2((float)cp[0], (float)cp[1]);
    }
    __syncthreads();

    const int tg = t0 + tgt;
    const float px = sxy[tg].x, py = sxy[tg].y;

    unsigned best[K];
#pragma unroll
    for (int k = 0; k < K; ++k) best[k] = 0xFFFFFFF0u + k;  // ascending tail

    const int s0 = sub * 64;
    float sf = (float)s0;
    for (int j = 0; j < 64; ++j) {
        const int s = s0 + j;
        const float2 c = sxy[s];                  // uniform -> broadcast
        const float dx = px - c.x, dy = py - c.y;
        const float keyf = fmaf(fmaf(dx, dx, dy * dy), 512.f, sf);  // exact
        sf += 1.f;
        unsigned key = (unsigned)keyf;
        if (s == tg) key = 0xFFFFFFFFu;           // loop=False (cndmask)
        chain_insert(best, key);
    }

    // stage A: subs 4-7 publish, subs 0-3 merge
    if (sub >= 4) {
#pragma unroll
        for (int k = 0; k < K; ++k) mk[sub - 4][tgt][k] = best[k];
    }
    __syncthreads();
    if (sub < 4) merge16(mk[sub][tgt], best);
    __syncthreads();
    // stage B: subs 2-3 publish, subs 0-1 merge
    if (sub == 2 || sub == 3) {
#pragma unroll
        for (int k = 0; k < K; ++k) mk[sub - 2][tgt][k] = best[k];
    }
    __syncthreads();
    if (sub < 2) merge16(mk[sub][tgt], best);
    __syncthreads();
    // stage C: sub 1 publishes, sub 0 merges + writes
    if (sub == 1) {
#pragma unroll
        for (int k = 0; k < K; ++k) mk[0][tgt][k] = best[k];
    }
    __syncthreads();
    if (sub == 0) {
        merge16(mk[0][tgt], best);
        int* op = idx_out + (size_t)(g * P + tg) * K;
#pragma unroll
        for (int k = 0; k < K; ++k) op[k] = (int)(best[k] & (unsigned)(P - 1));
    }
}

// ---------------------------------------------------------------------------
// cvt: x fp32 -> fp16, 8 elements/thread.
// ---------------------------------------------------------------------------
__global__ __launch_bounds__(256)
void cvt_kernel(const float* __restrict__ x, _Float16* __restrict__ x16, int n8) {
    const int i = blockIdx.x * 256 + threadIdx.x;
    if (i >= n8) return;
    const float4* p = (const float4*)(x + (size_t)i * 8);
    const float4 a = p[0], bq = p[1];
    half8 o;
    o[0] = (_Float16)a.x;  o[1] = (_Float16)a.y;
    o[2] = (_Float16)a.z;  o[3] = (_Float16)a.w;
    o[4] = (_Float16)bq.x; o[5] = (_Float16)bq.y;
    o[6] = (_Float16)bq.z; o[7] = (_Float16)bq.w;
    *(half8*)(x16 + (size_t)i * 8) = o;
}

// ---------------------------------------------------------------------------
// prep: [wl;wr] fp32 -> fp16 MFMA B-fragment layout.
// frag (ntile,kt): lane l holds B[kt*32+(l>>4)*8+j][ntile*16+(l&15)], j=0..7.
// ---------------------------------------------------------------------------
template <int NT, int KT, int NIN, int NOUT>
__global__ __launch_bounds__(256)
void prep_kernel(const float* __restrict__ wl, const float* __restrict__ wr,
                 _Float16* __restrict__ wf) {
    const int e = blockIdx.x * 256 + threadIdx.x;
    if (e >= NT * KT * 512) return;
    const int fr   = e >> 9;
    const int lane = (e >> 3) & 63;
    const int j    = e & 7;
    const int ntile = fr / KT;
    const int kt    = fr - ntile * KT;
    const int k = kt * 32 + ((lane >> 4) << 3) + j;
    const int n = ntile * 16 + (lane & 15);
    const float v = (k < NIN) ? wl[k * NOUT + n] : wr[(k - NIN) * NOUT + n];
    wf[e] = (_Float16)v;
}

// ---------------------------------------------------------------------------
// Fused SAGE: out = relu([mean_nbr(h) | h] @ [wl;wr] + b), f16 MFMA.
// Block: 256 thr / 4 waves, 64 points. LDS holds ONLY the mean half
// (64 x 128-half rows = 16 KB, ^(row&15) chunk swizzle); the root half's
// A-fragments are read directly from global (block rows are L1-hot).
// Gather: 4 lanes/pt, contiguous 64B line groups, packed-f16 partial sums
// (2 groups of 8 neighbors) combined in fp32.
// ---------------------------------------------------------------------------
template <int CIN, int NOUT, bool FOUT16>
__global__ __launch_bounds__(256)
void sage_kernel(const _Float16* __restrict__ hin, const int* __restrict__ idxg,
                 const _Float16* __restrict__ wf, const float* __restrict__ bias,
                 void* __restrict__ hout) {
    constexpr int KTm = CIN / 32;     // mean-half MFMA k-steps
    constexpr int KT  = CIN / 16;     // total k-steps (mean + root)
    constexpr int NH  = NOUT / 32;    // N-tiles per wave
    constexpr int RS  = 128;          // LDS row stride (halves) = 16 chunks

    __shared__ _Float16 As[64 * RS];  // 16 KB

    const int tid = threadIdx.x;
    const int n0  = blockIdx.x * 64;
    const int g   = n0 >> 9;
    const _Float16* __restrict__ hg = hin + (size_t)(g * P) * CIN;

    const int pt = tid >> 2;
    const int q  = tid & 3;
    const int xs = pt & 15;

    // 16 neighbor indices -> registers
    const int4* ip = (const int4*)(idxg + (size_t)(n0 + pt) * K);
    const int4 na = ip[0], nb4 = ip[1], nc = ip[2], nd = ip[3];
    const int nn[16] = {na.x, na.y, na.z, na.w, nb4.x, nb4.y, nb4.z, nb4.w,
                        nc.x, nc.y, nc.z, nc.w, nd.x, nd.y, nd.z, nd.w};

#pragma unroll
    for (int c = 0; c < KTm; ++c) {
        const int ch = c * 32 + q * 8;
        half8 a0 = {}; half8 a1 = {};
#pragma unroll
        for (int k = 0; k < 8; ++k)
            a0 += *(const half8*)(hg + (size_t)nn[k] * CIN + ch);
#pragma unroll
        for (int k = 8; k < 16; ++k)
            a1 += *(const half8*)(hg + (size_t)nn[k] * CIN + ch);
        half8 m;
#pragma unroll
        for (int e = 0; e < 8; ++e)
            m[e] = (_Float16)(((float)a0[e] + (float)a1[e]) * 0.0625f);
        const int gl = (c * 4 + q) ^ xs;
        *(half8*)&As[pt * RS + gl * 8] = m;
    }

    const int l  = tid & 63;
    const int wv = tid >> 6;
    const int mh = wv & 1;
    const int nh = wv >> 1;
    const int lm = l & 15, lq = l >> 4;

    float bs[NH];
#pragma unroll
    for (int nt = 0; nt < NH; ++nt)
        bs[nt] = bias[nh * (NOUT / 2) + nt * 16 + lm];

    __syncthreads();

    floatx4 acc[2][NH];
#pragma unroll
    for (int mt = 0; mt < 2; ++mt)
#pragma unroll
        for (int nt = 0; nt < NH; ++nt) {
            floatx4 z = {0.f, 0.f, 0.f, 0.f};
            acc[mt][nt] = z;
        }

#pragma unroll
    for (int kt = 0; kt < KT; ++kt) {
        half8 bfr[NH];
#pragma unroll
        for (int nt = 0; nt < NH; ++nt) {
            const int ng = nh * NH + nt;
            bfr[nt] = *(const half8*)(wf + ((size_t)(ng * KT + kt) * 64 + l) * 8);
        }
#pragma unroll
        for (int mt = 0; mt < 2; ++mt) {
            const int row = mh * 32 + mt * 16 + lm;
            half8 a;
            if (kt < KTm) {
                const int gl = (kt * 4 + lq) ^ (row & 15);
                a = *(const half8*)&As[row * RS + gl * 8];
            } else {
                a = *(const half8*)(hin + (size_t)(n0 + row) * CIN +
                                    (kt - KTm) * 32 + lq * 8);
            }
#pragma unroll
            for (int nt = 0; nt < NH; ++nt)
                acc[mt][nt] = __builtin_amdgcn_mfma_f32_16x16x32_f16(
                    a, bfr[nt], acc[mt][nt], 0, 0, 0);
        }
    }

#pragma unroll
    for (int mt = 0; mt < 2; ++mt)
#pragma unroll
        for (int nt = 0; nt < NH; ++nt) {
            const int n = nh * (NOUT / 2) + nt * 16 + lm;
#pragma unroll
            for (int r = 0; r < 4; ++r) {
                const int p = n0 + mh * 32 + mt * 16 + lq * 4 + r;
                float v = acc[mt][nt][r] + bs[nt];
                v = v > 0.f ? v : 0.f;
                if constexpr (FOUT16)
                    ((_Float16*)hout)[(size_t)p * NOUT + n] = (_Float16)v;
                else
                    ((float*)hout)[(size_t)p * NOUT + n] = v;
            }
        }
}

// ---------------------------------------------------------------------------
// Head: per-graph max-pool (512 x 32, fp16 in) -> 32x32 MLP -> 32x3 (fp32).
// ---------------------------------------------------------------------------
__global__ __launch_bounds__(256)
void head_kernel(const _Float16* __restrict__ h3, const float* __restrict__ lw0,
                 const float* __restrict__ lb0, const float* __restrict__ lw1,
                 const float* __restrict__ lb1, float* __restrict__ out) {
    __shared__ float red[256];
    __shared__ float pooled[32];
    __shared__ float hid[32];
    const int g = blockIdx.x;
    const int t = threadIdx.x;
    const int c = t & 31;
    const int r = t >> 5;

    const _Float16* hb = h3 + (size_t)g * P * 32;
    float m = -3.4e38f;
    for (int p = r; p < P; p += 8) m = fmaxf(m, (float)hb[p * 32 + c]);
    red[t] = m;
    __syncthreads();
    if (r < 4) red[t] = fmaxf(red[t], red[t + 128]);
    __syncthreads();
    if (r < 2) red[t] = fmaxf(red[t], red[t + 64]);
    __syncthreads();
    if (r == 0) pooled[c] = fmaxf(red[t], red[t + 32]);
    __syncthreads();

    if (t < 32) {
        float a = lb0[t];
#pragma unroll
        for (int i = 0; i < 32; ++i) a += pooled[i] * lw0[i * 32 + t];
        hid[t] = a > 0.f ? a : 0.f;
    }
    __syncthreads();
    if (t < 3) {
        float a = lb1[t];
#pragma unroll
        for (int i = 0; i < 32; ++i) a += hid[i] * lw1[i * 3 + t];
        out[g * 3 + t] = a;
    }
}

// ---------------------------------------------------------------------------
extern "C" void kernel_launch(void* const* d_in, const int* in_sizes, int n_in,
                              void* d_out, int out_size, void* d_ws, size_t ws_size,
                              hipStream_t stream) {
    const float* x   = (const float*)d_in[0];
    const int*   coo = (const int*)  d_in[1];
    const float* wl0 = (const float*)d_in[2];
    const float* wr0 = (const float*)d_in[3];
    const float* b0  = (const float*)d_in[4];
    const float* wl1 = (const float*)d_in[5];
    const float* wr1 = (const float*)d_in[6];
    const float* b1  = (const float*)d_in[7];
    const float* wl2 = (const float*)d_in[8];
    const float* wr2 = (const float*)d_in[9];
    const float* b2  = (const float*)d_in[10];
    const float* lw0 = (const float*)d_in[11];
    const float* lb0 = (const float*)d_in[12];
    const float* lw1 = (const float*)d_in[13];
    const float* lb1 = (const float*)d_in[14];
    float* out = (float*)d_out;

    char* ws = (char*)d_ws;
    // Workspace (bytes):
    //   wf0 : 49,152      @ 0
    //   wf1 : 24,576      @ 49,152
    //   wf2 :  8,192      @ 73,728
    //   idx :  4,194,304  @ 81,920
    //   x16 : 16,777,216  @ 4,276,224   (65536 x 128 fp16)
    //   h1  : 12,582,912  @ 21,053,440  (fp16)
    //   h2  :  8,388,608  @ 33,636,352  (fp16)
    //   h3  :  4,194,304  @ 42,024,960  (fp16)  end ~46.2 MB
    _Float16* wf0 = (_Float16*)(ws + 0);
    _Float16* wf1 = (_Float16*)(ws + 49152);
    _Float16* wf2 = (_Float16*)(ws + 73728);
    int*      idx = (int*)     (ws + 81920);
    _Float16* x16 = (_Float16*)(ws + 4276224);
    _Float16* h1  = (_Float16*)(ws + 21053440);
    _Float16* h2  = (_Float16*)(ws + 33636352);
    _Float16* h3  = (_Float16*)(ws + 42024960);

    prep_kernel<6, 8, 128, 96><<<96, 256, 0, stream>>>(wl0, wr0, wf0);
    prep_kernel<4, 6,  96, 64><<<48, 256, 0, stream>>>(wl1, wr1, wf1);
    prep_kernel<2, 4,  64, 32><<<16, 256, 0, stream>>>(wl2, wr2, wf2);

    cvt_kernel<<<4096, 256, 0, stream>>>(x, x16, NPTS * 128 / 8);
    knn_kernel<<<G * 8, 512, 0, stream>>>(coo, idx);

    sage_kernel<128, 96, true><<<NPTS / 64, 256, 0, stream>>>(x16, idx, wf0, b0, h1);
    sage_kernel< 96, 64, true><<<NPTS / 64, 256, 0, stream>>>(h1,  idx, wf1, b1, h2);
    sage_kernel< 64, 32, true><<<NPTS / 64, 256, 0, stream>>>(h2,  idx, wf2, b2, h3);

    head_kernel<<<G, 256, 0, stream>>>(h3, lw0, lb0, lw1, lb1, out);
}